// Round 2
// baseline (451.593 us; speedup 1.0000x reference)
//
#include <hip/hip_runtime.h>
#include <hip/hip_bf16.h>

// Problem constants (from reference)
#define BB   4
#define FF   9
#define MPP  100
#define PP   12000
#define CC   64
#define NYY  400
#define NXX  400
#define NXO  4          // NX / POOL_W
#define NPIL (BB * PP)  // 48000
#define OUTN (BB * CC * NYY * NXO)  // 409600
#define CNTN (BB * NYY * NXO)       // 6400

// One block = 64 pillars, 512 threads = 8 waves; wave w owns channels [w*8, w*8+8).
// Phase 1: per-pillar PointNet (dot over F=9, max over MP=100, BN+ReLU folded via
//          monotone-affine trick on zmin/zmax). feat -> LDS (stride 65: conflict-free).
// Phase 2: 64x64 channel mix (w2) from LDS, then BN2+ReLU and scatter-max (atomicMax
//          on fp32 bits, valid since values >= 0 post-ReLU) into the pooled output grid.
__global__ __launch_bounds__(512, 1) void pillar_kernel(
    const float* __restrict__ x,
    const int* __restrict__ coords,
    const float* __restrict__ w1, const float* __restrict__ b1,
    const float* __restrict__ g1, const float* __restrict__ be1,
    const float* __restrict__ m1, const float* __restrict__ v1,
    const float* __restrict__ w2, const float* __restrict__ b2,
    const float* __restrict__ g2, const float* __restrict__ be2,
    const float* __restrict__ m2, const float* __restrict__ v2,
    unsigned int* __restrict__ maxbuf, int* __restrict__ cnt)
{
    __shared__ float feat_lds[64 * 65];   // [pillar][channel], +1 pad -> conflict-free
    __shared__ float w2_lds[CC * CC];     // w2 copy, wave-uniform broadcast reads

    const int t    = threadIdx.x;
    const int lane = t & 63;
    const int wv   = t >> 6;                       // 0..7
    const int v    = blockIdx.x * 64 + lane;       // global pillar id (b*P + p)
    const int b    = v / PP;
    const int p    = v - b * PP;

    // stage w2 -> LDS (8 elems/thread)
    for (int i = t; i < CC * CC; i += 512) w2_lds[i] = w2[i];

    // w1 rows for this wave's 8 channels, resident in VGPRs (72 floats)
    float w1r[8][9];
    #pragma unroll
    for (int cl = 0; cl < 8; ++cl) {
        const int c = wv * 8 + cl;
        #pragma unroll
        for (int f = 0; f < 9; ++f) w1r[cl][f] = w1[c * 9 + f];
    }

    float zmx[8], zmn[8];
    #pragma unroll
    for (int cl = 0; cl < 8; ++cl) { zmx[cl] = -3.0e38f; zmn[cl] = 3.0e38f; }

    // x[b][f][mp][p]: lane = p -> coalesced; uniform offset (f*MP+mp)*P in SGPR
    const float* xp = x + (size_t)b * (FF * MPP * PP) + p;
    for (int mp = 0; mp < MPP; ++mp) {
        float xf[9];
        #pragma unroll
        for (int f = 0; f < 9; ++f) xf[f] = xp[(f * MPP + mp) * PP];
        #pragma unroll
        for (int cl = 0; cl < 8; ++cl) {
            float z = xf[0] * w1r[cl][0];
            #pragma unroll
            for (int f = 1; f < 9; ++f) z = fmaf(xf[f], w1r[cl][f], z);
            zmx[cl] = fmaxf(zmx[cl], z);
            zmn[cl] = fminf(zmn[cl], z);
        }
    }

    // BN1 + ReLU + max over mp (monotone affine: pick zmax if s1>=0 else zmin)
    #pragma unroll
    for (int cl = 0; cl < 8; ++cl) {
        const int c = wv * 8 + cl;
        const float s1 = g1[c] * rsqrtf(v1[c] + 1e-3f);
        const float t1 = be1[c] - m1[c] * s1;
        const float zsel = (s1 >= 0.f) ? zmx[cl] : zmn[cl];
        const float feat = fmaxf(0.f, fmaf(s1, zsel + b1[c], t1));
        feat_lds[lane * 65 + c] = feat;
    }
    __syncthreads();

    // channel mix: this thread computes d = wv*8+dl for pillar `lane`
    float acc[8];
    #pragma unroll
    for (int dl = 0; dl < 8; ++dl) acc[dl] = 0.f;
    for (int c = 0; c < CC; ++c) {
        const float fv = feat_lds[lane * 65 + c];        // lane-varying, stride 65
        #pragma unroll
        for (int dl = 0; dl < 8; ++dl)
            acc[dl] = fmaf(fv, w2_lds[(wv * 8 + dl) * CC + c], acc[dl]);  // broadcast
    }

    const int cb = coords[v * 4 + 0];
    const int cy = coords[v * 4 + 2];
    const int cx = coords[v * 4 + 3];
    const int xo = cx / 100;   // which pool window along x

    #pragma unroll
    for (int dl = 0; dl < 8; ++dl) {
        const int d = wv * 8 + dl;
        const float s2 = g2[d] * rsqrtf(v2[d] + 1e-3f);
        const float t2 = be2[d] - m2[d] * s2;
        const float val = fmaxf(0.f, fmaf(s2, acc[dl] + b2[d], t2));
        // val >= 0 -> fp32 bit pattern is monotone under unsigned compare
        atomicMax(&maxbuf[((cb * CC + d) * NYY + cy) * NXO + xo], __float_as_uint(val));
    }
    // window occupancy count (one thread per pillar)
    if (t < 64) atomicAdd(&cnt[(cb * NYY + cy) * NXO + xo], 1);
}

// out[b][d][y][xo] = max(maxbuf, zval[d] if window has at least one empty cell)
__global__ __launch_bounds__(256) void finalize_kernel(
    const unsigned int* __restrict__ maxbuf, const int* __restrict__ cnt,
    const float* __restrict__ b2, const float* __restrict__ g2,
    const float* __restrict__ be2, const float* __restrict__ m2,
    const float* __restrict__ v2, float* __restrict__ out)
{
    const int idx = blockIdx.x * 256 + threadIdx.x;   // < OUTN (exact)
    const int xo = idx & 3;
    const int tt = idx >> 2;           // (b*64+d)*400 + y
    const int y  = tt % NYY;
    const int bd = tt / NYY;
    const int d  = bd & 63;
    const int b  = bd >> 6;

    const float s2 = g2[d] * rsqrtf(v2[d] + 1e-3f);
    const float t2 = be2[d] - m2[d] * s2;
    const float zval = fmaxf(0.f, fmaf(s2, b2[d], t2));  // empty-cell value (>=0)

    const float mv = __uint_as_float(maxbuf[idx]);
    const int   cv = cnt[(b * NYY + y) * NXO + xo];
    const float r  = (cv >= 100) ? mv : fmaxf(mv, zval);
    out[idx] = r;
}

extern "C" void kernel_launch(void* const* d_in, const int* in_sizes, int n_in,
                              void* d_out, int out_size, void* d_ws, size_t ws_size,
                              hipStream_t stream) {
    const float* x   = (const float*)d_in[0];
    const int*   cds = (const int*)d_in[1];
    const float* w1  = (const float*)d_in[2];
    const float* b1  = (const float*)d_in[3];
    const float* g1  = (const float*)d_in[4];
    const float* be1 = (const float*)d_in[5];
    const float* m1  = (const float*)d_in[6];
    const float* v1  = (const float*)d_in[7];
    const float* w2  = (const float*)d_in[8];
    const float* b2  = (const float*)d_in[9];
    const float* g2  = (const float*)d_in[10];
    const float* be2 = (const float*)d_in[11];
    const float* m2  = (const float*)d_in[12];
    const float* v2  = (const float*)d_in[13];

    unsigned int* maxbuf = (unsigned int*)d_ws;
    int*          cnt    = (int*)d_ws + OUTN;

    // ws is re-poisoned to 0xAA before every timed launch: must zero every call.
    // uint 0 == fp32 0.0f, the correct identity for the >=0 max-scatter.
    hipMemsetAsync(d_ws, 0, (size_t)(OUTN + CNTN) * sizeof(unsigned int), stream);

    pillar_kernel<<<NPIL / 64, 512, 0, stream>>>(
        x, cds, w1, b1, g1, be1, m1, v1, w2, b2, g2, be2, m2, v2, maxbuf, cnt);

    finalize_kernel<<<OUTN / 256, 256, 0, stream>>>(
        maxbuf, cnt, b2, g2, be2, m2, v2, (float*)d_out);
}

// Round 3
// 379.410 us; speedup vs baseline: 1.1902x; 1.1902x over previous
//
#include <hip/hip_runtime.h>
#include <hip/hip_bf16.h>

// Problem constants
#define BB   4
#define FF   9
#define MPP  100
#define PP   12000
#define CC   64
#define NYY  400
#define NXO  4
#define NPIL (BB * PP)              // 48000
#define OUTN (BB * CC * NYY * NXO)  // 409600
#define CNTN (BB * NYY * NXO)       // 6400

// ws layout (byte offsets)
#define WS_MAXBUF 0
#define WS_CNT    (OUTN * 4)
#define WS_BIAS1  (WS_CNT + CNTN * 4)      // 64 fp32
#define WS_BIAS2  (WS_BIAS1 + 256)         // 64 fp32
#define WS_W1PB   (WS_BIAS2 + 256)         // 64x16 bf16 (s1-folded, K-padded)
#define WS_W2PB   (WS_W1PB + 2048)         // 64x64 bf16 (s2-folded)

typedef __attribute__((ext_vector_type(8)))  short short8;   // 8 bf16 = 4 VGPRs
typedef __attribute__((ext_vector_type(16))) float float16;  // MFMA 32x32 acc

__device__ __forceinline__ short f2bf(float v) {
    __hip_bfloat16 h = __float2bfloat16(v);
    short s; __builtin_memcpy(&s, &h, 2); return s;
}

// Fold BN scales into weights once per call (ws is re-poisoned every launch).
__global__ void prep_kernel(const float* __restrict__ w1, const float* __restrict__ b1,
                            const float* __restrict__ g1, const float* __restrict__ be1,
                            const float* __restrict__ m1, const float* __restrict__ v1,
                            const float* __restrict__ w2, const float* __restrict__ b2,
                            const float* __restrict__ g2, const float* __restrict__ be2,
                            const float* __restrict__ m2, const float* __restrict__ v2,
                            char* __restrict__ ws)
{
    float* bias1 = (float*)(ws + WS_BIAS1);
    float* bias2 = (float*)(ws + WS_BIAS2);
    short* w1pb  = (short*)(ws + WS_W1PB);
    short* w2pb  = (short*)(ws + WS_W2PB);
    const int t = threadIdx.x;   // 256
    if (t < 64) {
        const float s1 = g1[t] * rsqrtf(v1[t] + 1e-3f);
        bias1[t] = s1 * b1[t] + (be1[t] - m1[t] * s1);
        #pragma unroll
        for (int f = 0; f < 16; ++f)
            w1pb[t * 16 + f] = (f < 9) ? f2bf(s1 * w1[t * 9 + f]) : (short)0;
        const float s2 = g2[t] * rsqrtf(v2[t] + 1e-3f);
        bias2[t] = s2 * b2[t] + (be2[t] - m2[t] * s2);
    }
    for (int i = t; i < CC * CC; i += 256) {
        const int d = i >> 6;
        const float s2 = g2[d] * rsqrtf(v2[d] + 1e-3f);
        w2pb[i] = f2bf(s2 * w2[i]);
    }
}

// Block = 128 threads (2 waves), 32 pillars. Waves split the mp loop 50/50.
// Stage1: z' = (s1*w1)bf16 . x_bf16 via mfma_32x32x16, running max in 32 acc regs.
// LDS max-reduce -> feat = relu(max + bias1), bf16 -> stage2 K=64 MFMA chain with
// s2-folded w2; scatter-max (>=0 fp32 bits as uint) into pooled grid + window count.
__global__ __launch_bounds__(128, 3) void pillar_kernel(
    const float* __restrict__ x, const int* __restrict__ coords,
    const char* __restrict__ ws_ro,
    unsigned int* __restrict__ maxbuf, int* __restrict__ cnt)
{
    __shared__ float red[2 * 2048];        // [wave][ch][p] z'-max copies (16 KB)
    __shared__ short featbT[32 * 72];      // bf16 feat [p][c], stride 72 (16B-aligned rows)

    const float* bias1 = (const float*)(ws_ro + WS_BIAS1);
    const float* bias2 = (const float*)(ws_ro + WS_BIAS2);
    const short* w1pb  = (const short*)(ws_ro + WS_W1PB);
    const short* w2pb  = (const short*)(ws_ro + WS_W2PB);

    const int t    = threadIdx.x;
    const int lane = t & 63;
    const int wv   = t >> 6;          // 0..1
    const int half = lane >> 5;       // k-group
    const int pcol = lane & 31;       // pillar column (n) / channel row (m)
    const int v0   = blockIdx.x * 32; // first pillar of block (never straddles batch)
    const int b    = v0 / PP;
    const int p0   = v0 - b * PP;

    // A fragments: w1' rows for ch 0..31 and 32..63; k-slot = half*8+j (pad 9..15 = 0)
    const short8 a0 = *(const short8*)(w1pb + pcol * 16 + half * 8);
    const short8 a1 = *(const short8*)(w1pb + (pcol + 32) * 16 + half * 8);

    float16 vmx0, vmx1;
    #pragma unroll
    for (int r = 0; r < 16; ++r) { vmx0[r] = -3.0e38f; vmx1[r] = -3.0e38f; }

    // x[b][f][mp][p0+pcol]; element f at stride MPP*PP floats
    const float* xptr = x + ((size_t)b * FF * MPP + wv * 50) * PP + p0 + pcol;
    for (int mp = 0; mp < 50; ++mp) {
        float xv[8];
        if (half == 0) {
            #pragma unroll
            for (int j = 0; j < 8; ++j) xv[j] = xptr[(size_t)j * (MPP * PP)];
        } else {
            xv[0] = xptr[(size_t)8 * (MPP * PP)];
            #pragma unroll
            for (int j = 1; j < 8; ++j) xv[j] = 0.f;
        }
        short8 bf;
        #pragma unroll
        for (int j = 0; j < 8; ++j) bf[j] = f2bf(xv[j]);
        const float16 z0 = __builtin_amdgcn_mfma_f32_32x32x16_bf16(a0, bf, (float16)0.f, 0, 0, 0);
        const float16 z1 = __builtin_amdgcn_mfma_f32_32x32x16_bf16(a1, bf, (float16)0.f, 0, 0, 0);
        #pragma unroll
        for (int r = 0; r < 16; ++r) {
            vmx0[r] = fmaxf(vmx0[r], z0[r]);
            vmx1[r] = fmaxf(vmx1[r], z1[r]);
        }
        xptr += PP;
    }

    // D layout (HW-verified): col=lane&31, row=(r&3)+8*(r>>2)+4*(lane>>5)
    #pragma unroll
    for (int r = 0; r < 16; ++r) {
        const int ch = (r & 3) + 8 * (r >> 2) + 4 * half;
        red[wv * 2048 + ch * 32 + pcol]        = vmx0[r];
        red[wv * 2048 + (ch + 32) * 32 + pcol] = vmx1[r];
    }
    __syncthreads();

    // reduce 2 wave-copies, BN1 bias + ReLU, bf16, store transposed [p][c]
    {
        const int p  = t & 31;
        const int cg = t >> 5;      // 0..3, 16 channels each
        #pragma unroll
        for (int j = 0; j < 16; ++j) {
            const int c = cg * 16 + j;
            const float m = fmaxf(red[c * 32 + p], red[2048 + c * 32 + p]);
            featbT[p * 72 + c] = f2bf(fmaxf(0.f, m + bias1[c]));
        }
    }
    __syncthreads();

    // Stage2: wave wv computes d-tile wv (d = wv*32 .. +31), K = 64 in 4 chunks
    const short8 wa0 = *(const short8*)(w2pb + (wv * 32 + pcol) * 64 +  0 + half * 8);
    const short8 wa1 = *(const short8*)(w2pb + (wv * 32 + pcol) * 64 + 16 + half * 8);
    const short8 wa2 = *(const short8*)(w2pb + (wv * 32 + pcol) * 64 + 32 + half * 8);
    const short8 wa3 = *(const short8*)(w2pb + (wv * 32 + pcol) * 64 + 48 + half * 8);
    const short8 fb0 = *(const short8*)(&featbT[pcol * 72 +  0 + half * 8]);
    const short8 fb1 = *(const short8*)(&featbT[pcol * 72 + 16 + half * 8]);
    const short8 fb2 = *(const short8*)(&featbT[pcol * 72 + 32 + half * 8]);
    const short8 fb3 = *(const short8*)(&featbT[pcol * 72 + 48 + half * 8]);

    float16 acc = (float16)0.f;
    acc = __builtin_amdgcn_mfma_f32_32x32x16_bf16(wa0, fb0, acc, 0, 0, 0);
    acc = __builtin_amdgcn_mfma_f32_32x32x16_bf16(wa1, fb1, acc, 0, 0, 0);
    acc = __builtin_amdgcn_mfma_f32_32x32x16_bf16(wa2, fb2, acc, 0, 0, 0);
    acc = __builtin_amdgcn_mfma_f32_32x32x16_bf16(wa3, fb3, acc, 0, 0, 0);

    // scatter-max into pooled output grid
    const int* c4 = coords + (size_t)(v0 + pcol) * 4;
    const int cb = c4[0];
    const int cy = c4[2];
    const int xo = c4[3] / 100;
    const int base = ((cb * CC) * NYY + cy) * NXO + xo;
    #pragma unroll
    for (int r = 0; r < 16; ++r) {
        const int d = wv * 32 + (r & 3) + 8 * (r >> 2) + 4 * half;
        const float val = fmaxf(0.f, acc[r] + bias2[d]);
        atomicMax(&maxbuf[base + d * (NYY * NXO)], __float_as_uint(val));
    }
    if (t < 32) atomicAdd(&cnt[(cb * NYY + cy) * NXO + xo], 1);
}

// out = max(maxbuf, zval[d] if the 100-wide window has at least one empty cell)
__global__ __launch_bounds__(256) void finalize_kernel(
    const unsigned int* __restrict__ maxbuf, const int* __restrict__ cnt,
    const float* __restrict__ b2, const float* __restrict__ g2,
    const float* __restrict__ be2, const float* __restrict__ m2,
    const float* __restrict__ v2, float* __restrict__ out)
{
    const int idx = blockIdx.x * 256 + threadIdx.x;   // < OUTN exact
    const int xo = idx & 3;
    const int tt = idx >> 2;
    const int y  = tt % NYY;
    const int bd = tt / NYY;
    const int d  = bd & 63;
    const int b  = bd >> 6;

    const float s2 = g2[d] * rsqrtf(v2[d] + 1e-3f);
    const float t2 = be2[d] - m2[d] * s2;
    const float zval = fmaxf(0.f, fmaf(s2, b2[d], t2));

    const float mv = __uint_as_float(maxbuf[idx]);
    const int   cv = cnt[(b * NYY + y) * NXO + xo];
    out[idx] = (cv >= 100) ? mv : fmaxf(mv, zval);
}

extern "C" void kernel_launch(void* const* d_in, const int* in_sizes, int n_in,
                              void* d_out, int out_size, void* d_ws, size_t ws_size,
                              hipStream_t stream) {
    const float* x   = (const float*)d_in[0];
    const int*   cds = (const int*)d_in[1];
    const float* w1  = (const float*)d_in[2];
    const float* b1  = (const float*)d_in[3];
    const float* g1  = (const float*)d_in[4];
    const float* be1 = (const float*)d_in[5];
    const float* m1  = (const float*)d_in[6];
    const float* v1  = (const float*)d_in[7];
    const float* w2  = (const float*)d_in[8];
    const float* b2  = (const float*)d_in[9];
    const float* g2  = (const float*)d_in[10];
    const float* be2 = (const float*)d_in[11];
    const float* m2  = (const float*)d_in[12];
    const float* v2  = (const float*)d_in[13];

    char* ws = (char*)d_ws;
    unsigned int* maxbuf = (unsigned int*)(ws + WS_MAXBUF);
    int*          cnt    = (int*)(ws + WS_CNT);

    // zero maxbuf+cnt (uint 0 == fp32 0.0f, identity for >=0 max-scatter)
    hipMemsetAsync(ws, 0, (size_t)WS_BIAS1, stream);

    prep_kernel<<<1, 256, 0, stream>>>(w1, b1, g1, be1, m1, v1,
                                       w2, b2, g2, be2, m2, v2, ws);

    pillar_kernel<<<NPIL / 32, 128, 0, stream>>>(x, cds, ws, maxbuf, cnt);

    finalize_kernel<<<OUTN / 256, 256, 0, stream>>>(
        maxbuf, cnt, b2, g2, be2, m2, v2, (float*)d_out);
}